// Round 9
// baseline (400.400 us; speedup 1.0000x reference)
//
#include <hip/hip_runtime.h>
#include <math.h>

#define DIM 768
#define HEADS 12
#define SEQ 2048
#define ROWS 4096
#define LN_EPS 1e-5f

typedef __attribute__((ext_vector_type(8))) short short8;
typedef __attribute__((ext_vector_type(4))) float floatx4;
typedef unsigned short ushort_t;

__device__ __forceinline__ ushort_t f2bf(float x) {
    unsigned u = __float_as_uint(x);
    u += 0x7fff + ((u >> 16) & 1);
    return (ushort_t)(u >> 16);
}

__device__ __forceinline__ void gload_lds16(const void* g, void* l) {
    __builtin_amdgcn_global_load_lds((const __attribute__((address_space(1))) void*)g,
                                     (__attribute__((address_space(3))) void*)l, 16, 0, 0);
}

// ---------- fused prep: weight convert (0..1727) + gelev (1728..1743) + ln1 (1744..5839) ----------
__launch_bounds__(256)
__global__ void prep_all(const float* __restrict__ w0, const float* __restrict__ w1,
                         const float* __restrict__ w2, const float* __restrict__ w3,
                         ushort_t* __restrict__ t0, ushort_t* __restrict__ t1,
                         ushort_t* __restrict__ t2, ushort_t* __restrict__ t3,
                         const float* __restrict__ elev, const float* __restrict__ barrier_p,
                         float* __restrict__ G, float* __restrict__ C2,
                         const float* __restrict__ x, const float* __restrict__ ln1_g,
                         const float* __restrict__ ln1_b, ushort_t* __restrict__ h) {
    __shared__ __align__(16) ushort_t s[64][72];
    int bid = blockIdx.x;
    int t = threadIdx.x;
    if (bid < 1728) {
        const float* W; ushort_t* WT; int K, N, nx, id;
        if (bid < 432)       { W = w0; WT = t0; K = 768;  N = 2304; nx = 36; id = bid; }
        else if (bid < 576)  { W = w1; WT = t1; K = 768;  N = 768;  nx = 12; id = bid - 432; }
        else if (bid < 1152) { W = w2; WT = t2; K = 768;  N = 3072; nx = 48; id = bid - 576; }
        else                 { W = w3; WT = t3; K = 3072; N = 768;  nx = 12; id = bid - 1152; }
        int tx = id % nx, ty = id / nx;
        int k0 = ty * 64, n0 = tx * 64;
        int rr0 = t >> 4, c4 = (t & 15) * 4;
        for (int rr = rr0; rr < 64; rr += 16) {
            float4 w = *(const float4*)(W + (size_t)(k0 + rr) * N + n0 + c4);
            s[c4 + 0][rr] = f2bf(w.x); s[c4 + 1][rr] = f2bf(w.y);
            s[c4 + 2][rr] = f2bf(w.z); s[c4 + 3][rr] = f2bf(w.w);
        }
        __syncthreads();
        int nl = t >> 2, kq = (t & 3) * 16;
        uint4 a = *(const uint4*)&s[nl][kq];
        uint4 b = *(const uint4*)&s[nl][kq + 8];
        *(uint4*)(WT + (size_t)(n0 + nl) * K + k0 + kq) = a;
        *(uint4*)(WT + (size_t)(n0 + nl) * K + k0 + kq + 8) = b;
    } else if (bid < 1744) {
        int i = (bid - 1728) * 256 + t;
        float be = barrier_p[0] * elev[i];
        G[i]  = __expf(be);
        C2[i] = be;
    } else {
        int row = bid - 1744;
        const float* xr = x + (size_t)row * DIM;
        float v0 = xr[t], v1 = xr[t + 256], v2 = xr[t + 512];
        float sm  = v0 + v1 + v2;
        float ss = v0 * v0 + v1 * v1 + v2 * v2;
        #pragma unroll
        for (int o = 32; o >= 1; o >>= 1) { sm += __shfl_xor(sm, o); ss += __shfl_xor(ss, o); }
        __shared__ float rs[4], rss[4];
        int wid = t >> 6, lane = t & 63;
        if (lane == 0) { rs[wid] = sm; rss[wid] = ss; }
        __syncthreads();
        if (t == 0) {
            float S = 0.f, SS = 0.f;
            for (int i2 = 0; i2 < 4; i2++) { S += rs[i2]; SS += rss[i2]; }
            rs[0] = S; rss[0] = SS;
        }
        __syncthreads();
        float mean = rs[0] * (1.0f / DIM);
        float var  = rss[0] * (1.0f / DIM) - mean * mean;
        float rstd = rsqrtf(var + LN_EPS);
        ushort_t* orow = h + (size_t)row * DIM;
        orow[t]       = f2bf((v0 - mean) * rstd * ln1_g[t]       + ln1_b[t]);
        orow[t + 256] = f2bf((v1 - mean) * rstd * ln1_g[t + 256] + ln1_b[t + 256]);
        orow[t + 512] = f2bf((v2 - mean) * rstd * ln1_g[t + 512] + ln1_b[t + 512]);
    }
}

// ---------- LayerNorm fp32 in -> bf16 out (ln2) ----------
__launch_bounds__(256)
__global__ void ln_kernel(const float* __restrict__ x, const float* __restrict__ g,
                          const float* __restrict__ b, ushort_t* __restrict__ out) {
    int row = blockIdx.x;
    const float* xr = x + (size_t)row * DIM;
    int t = threadIdx.x;
    float v0 = xr[t], v1 = xr[t + 256], v2 = xr[t + 512];
    float s  = v0 + v1 + v2;
    float ss = v0 * v0 + v1 * v1 + v2 * v2;
    #pragma unroll
    for (int o = 32; o >= 1; o >>= 1) { s += __shfl_xor(s, o); ss += __shfl_xor(ss, o); }
    __shared__ float rs[4], rss[4];
    int wid = t >> 6, lane = t & 63;
    if (lane == 0) { rs[wid] = s; rss[wid] = ss; }
    __syncthreads();
    if (t == 0) {
        float S = 0.f, SS = 0.f;
        for (int i = 0; i < 4; i++) { S += rs[i]; SS += rss[i]; }
        rs[0] = S; rss[0] = SS;
    }
    __syncthreads();
    float mean = rs[0] * (1.0f / DIM);
    float var  = rss[0] * (1.0f / DIM) - mean * mean;
    float rstd = rsqrtf(var + LN_EPS);
    ushort_t* orow = out + (size_t)row * DIM;
    orow[t]       = f2bf((v0 - mean) * rstd * g[t]       + b[t]);
    orow[t + 256] = f2bf((v1 - mean) * rstd * g[t + 256] + b[t + 256]);
    orow[t + 512] = f2bf((v2 - mean) * rstd * g[t + 512] + b[t + 512]);
}

// ---------- 128x128 GEMM, 16x16x32 MFMA, A direct-from-global, B via LDS dbuf ----------
// EPI 0: qkv scatter   EPI 1: gelu -> bf16

#define G16_PREB(K0, SB)                                                              \
    {                                                                                 \
        int c0_ = t, r0_ = c0_ >> 2, bl0_ = c0_ & 3;                                  \
        int sw0_ = bl0_ ^ ((r0_ ^ (r0_ >> 2)) & 3);                                   \
        gload_lds16(WT + (size_t)(col0 + r0_) * K + (K0) + (sw0_ << 3), &SB[c0_ * 8]); \
        int c1_ = 256 + t, r1_ = c1_ >> 2, bl1_ = c1_ & 3;                            \
        int sw1_ = bl1_ ^ ((r1_ ^ (r1_ >> 2)) & 3);                                   \
        gload_lds16(WT + (size_t)(col0 + r1_) * K + (K0) + (sw1_ << 3), &SB[c1_ * 8]); \
    }

#define G16_LOADA(K0, AR)                                                             \
    {                                                                                 \
        _Pragma("unroll")                                                             \
        for (int i_ = 0; i_ < 4; i_++) AR[i_] = *(const short8*)(Arow[i_] + (K0));    \
    }

#define G16_COMP(AR, SB)                                                              \
    {                                                                                 \
        short8 b_[4];                                                                 \
        _Pragma("unroll")                                                             \
        for (int j_ = 0; j_ < 4; j_++) {                                              \
            int rb_ = wn * 64 + j_ * 16 + cl;                                         \
            b_[j_] = *(const short8*)&SB[rb_ * 32 + ((quad ^ ((rb_ ^ (rb_ >> 2)) & 3)) << 3)]; \
        }                                                                             \
        _Pragma("unroll")                                                             \
        for (int i_ = 0; i_ < 4; i_++)                                                \
            _Pragma("unroll")                                                         \
            for (int j_ = 0; j_ < 4; j_++)                                            \
                acc[i_][j_] = __builtin_amdgcn_mfma_f32_16x16x32_bf16(AR[i_], b_[j_], acc[i_][j_], 0, 0, 0); \
    }

template<int EPI>
__launch_bounds__(256)
__global__ void gemm16(const ushort_t* __restrict__ A, const ushort_t* __restrict__ WT,
                       const float* __restrict__ bias, ushort_t* __restrict__ outB,
                       ushort_t* __restrict__ qb, ushort_t* __restrict__ kb,
                       ushort_t* __restrict__ vb, int N, int K) {
    __shared__ __align__(16) ushort_t sB0[128 * 32];
    __shared__ __align__(16) ushort_t sB1[128 * 32];
    int t = threadIdx.x;
    int row0 = blockIdx.y * 128, col0 = blockIdx.x * 128;
    int wid = t >> 6, lane = t & 63;
    int wm = wid >> 1, wn = wid & 1;
    int cl = lane & 15, quad = lane >> 4;

    const ushort_t* Arow[4];
    #pragma unroll
    for (int i = 0; i < 4; i++)
        Arow[i] = A + (size_t)(row0 + wm * 64 + i * 16 + cl) * K + quad * 8;

    floatx4 acc[4][4];
    #pragma unroll
    for (int i = 0; i < 4; i++)
        #pragma unroll
        for (int j = 0; j < 4; j++) { floatx4 z = {0.f, 0.f, 0.f, 0.f}; acc[i][j] = z; }

    short8 aA[4], aB[4];
    G16_PREB(0, sB0)
    G16_LOADA(0, aA)
    for (int k0 = 0; k0 < K; k0 += 64) {
        __syncthreads();
        if (k0 + 32 < K) G16_PREB(k0 + 32, sB1)
        G16_LOADA(k0 + 32 < K ? k0 + 32 : 0, aB)
        G16_COMP(aA, sB0)
        __syncthreads();
        if (k0 + 64 < K) G16_PREB(k0 + 64, sB0)
        G16_LOADA(k0 + 64 < K ? k0 + 64 : 0, aA)
        G16_COMP(aB, sB1)
    }

    #pragma unroll
    for (int i = 0; i < 4; i++) {
        #pragma unroll
        for (int j = 0; j < 4; j++) {
            int gcol = col0 + wn * 64 + j * 16 + cl;
            float bv = bias[gcol];
            #pragma unroll
            for (int rg = 0; rg < 4; rg++) {
                int grow = row0 + wm * 64 + i * 16 + quad * 4 + rg;
                float v = acc[i][j][rg] + bv;
                if (EPI == 0) {
                    int which = gcol / 768;
                    int hc = gcol - which * 768;
                    int hh = hc >> 6, d = hc & 63;
                    int b_ = grow >> 11, n = grow & 2047;
                    size_t bhh = (size_t)(b_ * 12 + hh);
                    if (which == 0)      qb[(bhh * 2048 + n) * 64 + d] = f2bf(v * 0.125f);
                    else if (which == 1) kb[(bhh * 2048 + n) * 64 + d] = f2bf(v);
                    else                 vb[(bhh * 64 + d) * 2048 + n] = f2bf(v);
                } else {
                    v = 0.5f * v * (1.f + erff(v * 0.70710678118654752f));
                    outB[(size_t)grow * N + gcol] = f2bf(v);
                }
            }
        }
    }
}

// ---------- 64x64 GEMM (proj/FC2), A direct-from-global, B via LDS dbuf ----------
#define GB_PREB(K0, SB)                                                               \
    {                                                                                 \
        int r_ = t >> 2, sub_ = t & 3;                                                \
        gload_lds16(WT + (size_t)(col0 + r_) * K + (K0) + sub_ * 8, &SB[t * 8]);      \
    }

#define GB_LOADA(K0, AR)                                                              \
    {                                                                                 \
        _Pragma("unroll")                                                             \
        for (int i_ = 0; i_ < 2; i_++) AR[i_] = *(const short8*)(Arow[i_] + (K0));    \
    }

#define GB_COMP(AR, SB)                                                               \
    {                                                                                 \
        short8 b_[2];                                                                 \
        _Pragma("unroll")                                                             \
        for (int j_ = 0; j_ < 2; j_++)                                                \
            b_[j_] = *(const short8*)&SB[(wn * 32 + j_ * 16 + cl) * 32 + quad * 8];   \
        _Pragma("unroll")                                                             \
        for (int i_ = 0; i_ < 2; i_++)                                                \
            _Pragma("unroll")                                                         \
            for (int j_ = 0; j_ < 2; j_++)                                            \
                acc[i_][j_] = __builtin_amdgcn_mfma_f32_16x16x32_bf16(AR[i_], b_[j_], acc[i_][j_], 0, 0, 0); \
    }

__launch_bounds__(256)
__global__ void gemm_bf16(const ushort_t* __restrict__ A, const ushort_t* __restrict__ WT,
                          const float* __restrict__ bias, const float* __restrict__ res,
                          float* __restrict__ outF, int N, int K) {
    __shared__ __align__(16) ushort_t sB0[64 * 32];
    __shared__ __align__(16) ushort_t sB1[64 * 32];
    int t = threadIdx.x;
    int row0 = blockIdx.y * 64, col0 = blockIdx.x * 64;
    int wid = t >> 6, lane = t & 63;
    int wm = wid >> 1, wn = wid & 1;
    int cl = lane & 15, quad = lane >> 4;

    const ushort_t* Arow[2];
    #pragma unroll
    for (int i = 0; i < 2; i++)
        Arow[i] = A + (size_t)(row0 + wm * 32 + i * 16 + cl) * K + quad * 8;

    floatx4 acc[2][2];
    #pragma unroll
    for (int i = 0; i < 2; i++)
        #pragma unroll
        for (int j = 0; j < 2; j++) { floatx4 z = {0.f, 0.f, 0.f, 0.f}; acc[i][j] = z; }

    short8 aA[2], aB[2];
    GB_PREB(0, sB0)
    GB_LOADA(0, aA)
    for (int k0 = 0; k0 < K; k0 += 64) {
        __syncthreads();
        if (k0 + 32 < K) GB_PREB(k0 + 32, sB1)
        GB_LOADA(k0 + 32 < K ? k0 + 32 : 0, aB)
        GB_COMP(aA, sB0)
        __syncthreads();
        if (k0 + 64 < K) GB_PREB(k0 + 64, sB0)
        GB_LOADA(k0 + 64 < K ? k0 + 64 : 0, aA)
        GB_COMP(aB, sB1)
    }

    #pragma unroll
    for (int i = 0; i < 2; i++) {
        #pragma unroll
        for (int j = 0; j < 2; j++) {
            int gcol = col0 + wn * 32 + j * 16 + cl;
            float bv = bias[gcol];
            #pragma unroll
            for (int rg = 0; rg < 4; rg++) {
                int grow = row0 + wm * 32 + i * 16 + quad * 4 + rg;
                float v = acc[i][j][rg] + bv + res[(size_t)grow * N + gcol];
                outF[(size_t)grow * N + gcol] = v;
            }
        }
    }
}

// ---------- MFMA flash attention: static dbuf + Q-frags hoisted to registers ----------
#define PREFETCH(K0N, KSN, VTN)                                                   \
    {                                                                             \
        const ushort_t* kbase_ = kb + (bh * 2048 + (K0N)) * 64;                   \
        const ushort_t* vbase_ = vb + bh * 131072 + (K0N);                        \
        int c0_ = t, r0_ = c0_ >> 3, b0_ = c0_ & 7;                               \
        gload_lds16(kbase_ + (r0_ << 6) + ((b0_ ^ (r0_ & 7)) << 3), &KSN[c0_ * 8]); \
        gload_lds16(vbase_ + (size_t)r0_ * 2048 + ((b0_ ^ (r0_ & 7)) << 3), &VTN[c0_ * 8]); \
        int c1_ = 256 + t, r1_ = c1_ >> 3, b1_ = c1_ & 7;                         \
        gload_lds16(kbase_ + (r1_ << 6) + ((b1_ ^ (r1_ & 7)) << 3), &KSN[c1_ * 8]); \
        gload_lds16(vbase_ + (size_t)r1_ * 2048 + ((b1_ ^ (r1_ & 7)) << 3), &VTN[c1_ * 8]); \
    }

// barrier at tile END: prefetch(kt+1) issued first, drained by that barrier;
// Ps write->read is wave-local (no barrier needed).
#define ATTN_TILE(KT, KSC, VTC, KSN, VTN)                                         \
    {                                                                             \
        if ((KT) < 31) PREFETCH(((KT) + 1) * 64, KSN, VTN)                        \
        float gjv_[4];                                                            \
        gjv_[0] = G[b * 2048 + (KT) * 64 + cl];                                   \
        gjv_[1] = G[b * 2048 + (KT) * 64 + 16 + cl];                              \
        gjv_[2] = G[b * 2048 + (KT) * 64 + 32 + cl];                              \
        gjv_[3] = G[b * 2048 + (KT) * 64 + 48 + cl];                              \
        floatx4 s_[4];                                                            \
        s_[0] = c2init; s_[1] = c2init; s_[2] = c2init; s_[3] = c2init;           \
        _Pragma("unroll")                                                         \
        for (int kh = 0; kh < 2; kh++) {                                          \
            short8 aq_ = (kh == 0) ? aq0 : aq1;                                   \
            _Pragma("unroll")                                                     \
            for (int nt = 0; nt < 4; nt++) {                                      \
                short8 bk_ = *(const short8*)&KSC[((nt * 16 + cl) << 6) + (((kh * 4 + quad) ^ (cl & 7)) << 3)]; \
                s_[nt] = __builtin_amdgcn_mfma_f32_16x16x32_bf16(aq_, bk_, s_[nt], 0, 0, 0); \
            }                                                                     \
        }                                                                         \
        _Pragma("unroll")                                                         \
        for (int rg = 0; rg < 4; rg++) {                                          \
            int prow_ = wid * 16 + quad * 4 + rg;                                 \
            int r8_ = prow_ & 7, pb_ = prow_ << 6, cs_ = cl & 7, ch_ = cl >> 3;   \
            _Pragma("unroll")                                                     \
            for (int nt = 0; nt < 4; nt++) {                                      \
                float tf_ = __expf(s_[nt][rg]);                                   \
                float p_  = tf_ * __builtin_amdgcn_rcpf(gi[rg] + gjv_[nt]);       \
                sem[rg] += p_;                                                    \
                Ps[pb_ + (((nt * 2 + ch_) ^ r8_) << 3) + cs_] = (ushort_t)(__float_as_uint(p_) >> 16); \
            }                                                                     \
        }                                                                         \
        _Pragma("unroll")                                                         \
        for (int kh = 0; kh < 2; kh++) {                                          \
            short8 ap_ = *(const short8*)&Ps[((wid * 16 + cl) << 6) + (((kh * 4 + quad) ^ (cl & 7)) << 3)]; \
            _Pragma("unroll")                                                     \
            for (int dt = 0; dt < 4; dt++) {                                      \
                short8 bv_ = *(const short8*)&VTC[((dt * 16 + cl) << 6) + (((kh * 4 + quad) ^ (cl & 7)) << 3)]; \
                o[dt] = __builtin_amdgcn_mfma_f32_16x16x32_bf16(ap_, bv_, o[dt], 0, 0, 0); \
            }                                                                     \
        }                                                                         \
        __syncthreads();                                                          \
    }

__launch_bounds__(256)
__global__ void attn_mfma(const ushort_t* __restrict__ qb, const ushort_t* __restrict__ kb,
                          const ushort_t* __restrict__ vb, const float* __restrict__ G,
                          const float* __restrict__ C2, ushort_t* __restrict__ attn) {
    __shared__ __align__(16) ushort_t Qs[4096];
    __shared__ __align__(16) ushort_t Ks0[4096];
    __shared__ __align__(16) ushort_t Ks1[4096];
    __shared__ __align__(16) ushort_t Vt0[4096];
    __shared__ __align__(16) ushort_t Vt1[4096];
    __shared__ __align__(16) ushort_t Ps[4096];
    int qt = blockIdx.x, h = blockIdx.y, b = blockIdx.z;
    int t = threadIdx.x, wid = t >> 6, lane = t & 63;
    int cl = lane & 15, quad = lane >> 4;
    int q0 = qt * 64;
    size_t bh = (size_t)(b * 12 + h);

    const ushort_t* qbase = qb + (bh * 2048 + q0) * 64;
    #pragma unroll
    for (int i = 0; i < 2; i++) {
        int c = i * 256 + t, row = c >> 3, blk = c & 7;
        gload_lds16(qbase + (row << 6) + ((blk ^ (row & 7)) << 3), &Qs[c * 8]);
    }
    int qrow4 = b * 2048 + q0 + wid * 16 + quad * 4;
    float4 g4  = *(const float4*)(G  + qrow4);
    float4 c24 = *(const float4*)(C2 + qrow4);
    float gi[4]  = {g4.x, g4.y, g4.z, g4.w};
    floatx4 c2init = {c24.x, c24.y, c24.z, c24.w};

    PREFETCH(0, Ks0, Vt0)
    __syncthreads();   // Q + tile0 resident

    // Q fragments are tile-invariant: hoist to registers (saves 2 LDS reads/tile)
    short8 aq0 = *(const short8*)&Qs[((wid * 16 + cl) << 6) + ((quad ^ (cl & 7)) << 3)];
    short8 aq1 = *(const short8*)&Qs[((wid * 16 + cl) << 6) + (((4 + quad) ^ (cl & 7)) << 3)];

    floatx4 o[4];
    #pragma unroll
    for (int j = 0; j < 4; j++) { floatx4 z = {0.f, 0.f, 0.f, 0.f}; o[j] = z; }
    float sem[4] = {0.f, 0.f, 0.f, 0.f};

    for (int kt = 0; kt < 32; kt += 2) {
        ATTN_TILE(kt,     Ks0, Vt0, Ks1, Vt1)
        ATTN_TILE(kt + 1, Ks1, Vt1, Ks0, Vt0)
    }

    #pragma unroll
    for (int rg = 0; rg < 4; rg++) {
        float m = sem[rg];
        #pragma unroll
        for (int off = 1; off < 16; off <<= 1) m += __shfl_xor(m, off);
        float inv = __builtin_amdgcn_rcpf(m);
        int grow = b * 2048 + q0 + wid * 16 + quad * 4 + rg;
        #pragma unroll
        for (int dt = 0; dt < 4; dt++)
            attn[(size_t)grow * 768 + h * 64 + dt * 16 + cl] = f2bf(o[dt][rg] * inv);
    }
}

extern "C" void kernel_launch(void* const* d_in, const int* in_sizes, int n_in,
                              void* d_out, int out_size, void* d_ws, size_t ws_size,
                              hipStream_t stream) {
    const float* x      = (const float*)d_in[0];
    const float* elev   = (const float*)d_in[1];
    const float* qkv_w  = (const float*)d_in[2];
    const float* qkv_b  = (const float*)d_in[3];
    const float* proj_w = (const float*)d_in[4];
    const float* proj_b = (const float*)d_in[5];
    const float* ln1_g  = (const float*)d_in[6];
    const float* ln1_b  = (const float*)d_in[7];
    const float* ln2_g  = (const float*)d_in[8];
    const float* ln2_b  = (const float*)d_in[9];
    const float* fc1_w  = (const float*)d_in[10];
    const float* fc1_b  = (const float*)d_in[11];
    const float* fc2_w  = (const float*)d_in[12];
    const float* fc2_b  = (const float*)d_in[13];
    const float* barrier= (const float*)d_in[14];
    float* out = (float*)d_out;
    char* ws = (char*)d_ws;

    ushort_t* h    = (ushort_t*)(ws + 0);
    ushort_t* qb   = (ushort_t*)(ws + 6291456);
    ushort_t* kb   = (ushort_t*)(ws + 12582912);
    ushort_t* vb   = (ushort_t*)(ws + 18874368);
    ushort_t* f1   = (ushort_t*)(ws + 0);         // overlays h,qb,kb,vb
    ushort_t* attn = (ushort_t*)(ws + 25165824);
    ushort_t* h2   = (ushort_t*)(ws + 31457280);
    float*    Gf   = (float*)(ws + 31457280);     // overlays h2 region, dead before ln2
    float*    C2f  = (float*)(ws + 31473664);
    ushort_t* qkvT = (ushort_t*)(ws + 37748736);
    ushort_t* projT= (ushort_t*)(ws + 41287680);
    ushort_t* fc1T = (ushort_t*)(ws + 42467328);
    ushort_t* fc2T = (ushort_t*)(ws + 47185920);

    prep_all<<<5840, 256, 0, stream>>>(qkv_w, proj_w, fc1_w, fc2_w, qkvT, projT, fc1T, fc2T,
                                       elev, barrier, Gf, C2f, x, ln1_g, ln1_b, h);
    gemm16<0><<<dim3(2304 / 128, 32), 256, 0, stream>>>(
        h, qkvT, qkv_b, nullptr, qb, kb, vb, 2304, 768);
    attn_mfma<<<dim3(32, HEADS, 2), 256, 0, stream>>>(qb, kb, vb, Gf, C2f, attn);
    gemm_bf16<<<dim3(768 / 64, 64), 256, 0, stream>>>(
        attn, projT, proj_b, x, out, 768, 768);
    ln_kernel<<<ROWS, 256, 0, stream>>>(out, ln2_g, ln2_b, h2);
    gemm16<1><<<dim3(3072 / 128, 32), 256, 0, stream>>>(
        h2, fc1T, fc1_b, f1, nullptr, nullptr, nullptr, 3072, 768);
    gemm_bf16<<<dim3(768 / 64, 64), 256, 0, stream>>>(
        f1, fc2T, fc2_b, out, out, 768, 3072);
}

// Round 10
// 314.779 us; speedup vs baseline: 1.2720x; 1.2720x over previous
//
#include <hip/hip_runtime.h>
#include <math.h>

#define DIM 768
#define HEADS 12
#define SEQ 2048
#define ROWS 4096
#define LN_EPS 1e-5f

typedef __attribute__((ext_vector_type(8))) short short8;
typedef __attribute__((ext_vector_type(4))) float floatx4;
typedef unsigned short ushort_t;

__device__ __forceinline__ ushort_t f2bf(float x) {
    unsigned u = __float_as_uint(x);
    u += 0x7fff + ((u >> 16) & 1);
    return (ushort_t)(u >> 16);
}

__device__ __forceinline__ void gload_lds16(const void* g, void* l) {
    __builtin_amdgcn_global_load_lds((const __attribute__((address_space(1))) void*)g,
                                     (__attribute__((address_space(3))) void*)l, 16, 0, 0);
}

// ---------- fused prep: weight convert (0..1727) + gelev (1728..1743) + ln1 (1744..5839) ----------
__launch_bounds__(256)
__global__ void prep_all(const float* __restrict__ w0, const float* __restrict__ w1,
                         const float* __restrict__ w2, const float* __restrict__ w3,
                         ushort_t* __restrict__ t0, ushort_t* __restrict__ t1,
                         ushort_t* __restrict__ t2, ushort_t* __restrict__ t3,
                         const float* __restrict__ elev, const float* __restrict__ barrier_p,
                         float* __restrict__ G, float* __restrict__ C2,
                         const float* __restrict__ x, const float* __restrict__ ln1_g,
                         const float* __restrict__ ln1_b, ushort_t* __restrict__ h) {
    __shared__ __align__(16) ushort_t s[64][72];
    int bid = blockIdx.x;
    int t = threadIdx.x;
    if (bid < 1728) {
        const float* W; ushort_t* WT; int K, N, nx, id;
        if (bid < 432)       { W = w0; WT = t0; K = 768;  N = 2304; nx = 36; id = bid; }
        else if (bid < 576)  { W = w1; WT = t1; K = 768;  N = 768;  nx = 12; id = bid - 432; }
        else if (bid < 1152) { W = w2; WT = t2; K = 768;  N = 3072; nx = 48; id = bid - 576; }
        else                 { W = w3; WT = t3; K = 3072; N = 768;  nx = 12; id = bid - 1152; }
        int tx = id % nx, ty = id / nx;
        int k0 = ty * 64, n0 = tx * 64;
        int rr0 = t >> 4, c4 = (t & 15) * 4;
        for (int rr = rr0; rr < 64; rr += 16) {
            float4 w = *(const float4*)(W + (size_t)(k0 + rr) * N + n0 + c4);
            s[c4 + 0][rr] = f2bf(w.x); s[c4 + 1][rr] = f2bf(w.y);
            s[c4 + 2][rr] = f2bf(w.z); s[c4 + 3][rr] = f2bf(w.w);
        }
        __syncthreads();
        int nl = t >> 2, kq = (t & 3) * 16;
        uint4 a = *(const uint4*)&s[nl][kq];
        uint4 b = *(const uint4*)&s[nl][kq + 8];
        *(uint4*)(WT + (size_t)(n0 + nl) * K + k0 + kq) = a;
        *(uint4*)(WT + (size_t)(n0 + nl) * K + k0 + kq + 8) = b;
    } else if (bid < 1744) {
        int i = (bid - 1728) * 256 + t;
        float be = barrier_p[0] * elev[i];
        G[i]  = __expf(be);
        C2[i] = be;
    } else {
        int row = bid - 1744;
        const float* xr = x + (size_t)row * DIM;
        float v0 = xr[t], v1 = xr[t + 256], v2 = xr[t + 512];
        float sm  = v0 + v1 + v2;
        float ss = v0 * v0 + v1 * v1 + v2 * v2;
        #pragma unroll
        for (int o = 32; o >= 1; o >>= 1) { sm += __shfl_xor(sm, o); ss += __shfl_xor(ss, o); }
        __shared__ float rs[4], rss[4];
        int wid = t >> 6, lane = t & 63;
        if (lane == 0) { rs[wid] = sm; rss[wid] = ss; }
        __syncthreads();
        if (t == 0) {
            float S = 0.f, SS = 0.f;
            for (int i2 = 0; i2 < 4; i2++) { S += rs[i2]; SS += rss[i2]; }
            rs[0] = S; rss[0] = SS;
        }
        __syncthreads();
        float mean = rs[0] * (1.0f / DIM);
        float var  = rss[0] * (1.0f / DIM) - mean * mean;
        float rstd = rsqrtf(var + LN_EPS);
        ushort_t* orow = h + (size_t)row * DIM;
        orow[t]       = f2bf((v0 - mean) * rstd * ln1_g[t]       + ln1_b[t]);
        orow[t + 256] = f2bf((v1 - mean) * rstd * ln1_g[t + 256] + ln1_b[t + 256]);
        orow[t + 512] = f2bf((v2 - mean) * rstd * ln1_g[t + 512] + ln1_b[t + 512]);
    }
}

// ---------- LayerNorm fp32 in -> bf16 out (ln2) ----------
__launch_bounds__(256)
__global__ void ln_kernel(const float* __restrict__ x, const float* __restrict__ g,
                          const float* __restrict__ b, ushort_t* __restrict__ out) {
    int row = blockIdx.x;
    const float* xr = x + (size_t)row * DIM;
    int t = threadIdx.x;
    float v0 = xr[t], v1 = xr[t + 256], v2 = xr[t + 512];
    float s  = v0 + v1 + v2;
    float ss = v0 * v0 + v1 * v1 + v2 * v2;
    #pragma unroll
    for (int o = 32; o >= 1; o >>= 1) { s += __shfl_xor(s, o); ss += __shfl_xor(ss, o); }
    __shared__ float rs[4], rss[4];
    int wid = t >> 6, lane = t & 63;
    if (lane == 0) { rs[wid] = s; rss[wid] = ss; }
    __syncthreads();
    if (t == 0) {
        float S = 0.f, SS = 0.f;
        for (int i = 0; i < 4; i++) { S += rs[i]; SS += rss[i]; }
        rs[0] = S; rss[0] = SS;
    }
    __syncthreads();
    float mean = rs[0] * (1.0f / DIM);
    float var  = rss[0] * (1.0f / DIM) - mean * mean;
    float rstd = rsqrtf(var + LN_EPS);
    ushort_t* orow = out + (size_t)row * DIM;
    orow[t]       = f2bf((v0 - mean) * rstd * g[t]       + b[t]);
    orow[t + 256] = f2bf((v1 - mean) * rstd * g[t + 256] + b[t + 256]);
    orow[t + 512] = f2bf((v2 - mean) * rstd * g[t + 512] + b[t + 512]);
}

// ---------- 128x128 GEMM, 16x16x32 MFMA, 4x4 acc/wave, LDS-staged A+B, static dbuf ----------
// EPI 0: qkv scatter   EPI 1: gelu -> bf16   EPI 2: bias + res(fp32) -> fp32

#define G16_PREFETCH(K0, SA, SB)                                                      \
    {                                                                                 \
        int c0_ = t, r0_ = c0_ >> 2, bl0_ = c0_ & 3;                                  \
        int sw0_ = bl0_ ^ ((r0_ ^ (r0_ >> 2)) & 3);                                   \
        gload_lds16(A  + (size_t)(row0 + r0_) * K + (K0) + (sw0_ << 3), &SA[c0_ * 8]); \
        gload_lds16(WT + (size_t)(col0 + r0_) * K + (K0) + (sw0_ << 3), &SB[c0_ * 8]); \
        int c1_ = 256 + t, r1_ = c1_ >> 2, bl1_ = c1_ & 3;                            \
        int sw1_ = bl1_ ^ ((r1_ ^ (r1_ >> 2)) & 3);                                   \
        gload_lds16(A  + (size_t)(row0 + r1_) * K + (K0) + (sw1_ << 3), &SA[c1_ * 8]); \
        gload_lds16(WT + (size_t)(col0 + r1_) * K + (K0) + (sw1_ << 3), &SB[c1_ * 8]); \
    }

#define G16_COMPUTE(SA, SB)                                                           \
    {                                                                                 \
        short8 a_[4], b_[4];                                                          \
        _Pragma("unroll")                                                             \
        for (int i = 0; i < 4; i++) {                                                 \
            int ra_ = wm * 64 + i * 16 + cl;                                          \
            a_[i] = *(const short8*)&SA[ra_ * 32 + ((quad ^ ((ra_ ^ (ra_ >> 2)) & 3)) << 3)]; \
        }                                                                             \
        _Pragma("unroll")                                                             \
        for (int j = 0; j < 4; j++) {                                                 \
            int rb_ = wn * 64 + j * 16 + cl;                                          \
            b_[j] = *(const short8*)&SB[rb_ * 32 + ((quad ^ ((rb_ ^ (rb_ >> 2)) & 3)) << 3)]; \
        }                                                                             \
        _Pragma("unroll")                                                             \
        for (int i = 0; i < 4; i++)                                                   \
            _Pragma("unroll")                                                         \
            for (int j = 0; j < 4; j++)                                               \
                acc[i][j] = __builtin_amdgcn_mfma_f32_16x16x32_bf16(a_[i], b_[j], acc[i][j], 0, 0, 0); \
    }

template<int EPI>
__launch_bounds__(256)
__global__ void gemm16(const ushort_t* __restrict__ A, const ushort_t* __restrict__ WT,
                       const float* __restrict__ bias, ushort_t* __restrict__ outB,
                       const float* __restrict__ res, float* __restrict__ outF,
                       ushort_t* __restrict__ qb, ushort_t* __restrict__ kb,
                       ushort_t* __restrict__ vb, int N, int K) {
    __shared__ __align__(16) ushort_t sA0[128 * 32];
    __shared__ __align__(16) ushort_t sA1[128 * 32];
    __shared__ __align__(16) ushort_t sB0[128 * 32];
    __shared__ __align__(16) ushort_t sB1[128 * 32];
    int t = threadIdx.x;
    int row0 = blockIdx.y * 128, col0 = blockIdx.x * 128;
    int wid = t >> 6, lane = t & 63;
    int wm = wid >> 1, wn = wid & 1;
    int cl = lane & 15, quad = lane >> 4;

    floatx4 acc[4][4];
    #pragma unroll
    for (int i = 0; i < 4; i++)
        #pragma unroll
        for (int j = 0; j < 4; j++) { floatx4 z = {0.f, 0.f, 0.f, 0.f}; acc[i][j] = z; }

    G16_PREFETCH(0, sA0, sB0)
    for (int k0 = 0; k0 < K; k0 += 64) {
        __syncthreads();
        if (k0 + 32 < K) G16_PREFETCH(k0 + 32, sA1, sB1)
        G16_COMPUTE(sA0, sB0)
        __syncthreads();
        if (k0 + 64 < K) G16_PREFETCH(k0 + 64, sA0, sB0)
        G16_COMPUTE(sA1, sB1)
    }

    #pragma unroll
    for (int i = 0; i < 4; i++) {
        #pragma unroll
        for (int j = 0; j < 4; j++) {
            int gcol = col0 + wn * 64 + j * 16 + cl;
            float bv = bias[gcol];
            #pragma unroll
            for (int rg = 0; rg < 4; rg++) {
                int grow = row0 + wm * 64 + i * 16 + quad * 4 + rg;
                float v = acc[i][j][rg] + bv;
                if (EPI == 0) {
                    int which = gcol / 768;
                    int hc = gcol - which * 768;
                    int hh = hc >> 6, d = hc & 63;
                    int b_ = grow >> 11, n = grow & 2047;
                    size_t bhh = (size_t)(b_ * 12 + hh);
                    if (which == 0)      qb[(bhh * 2048 + n) * 64 + d] = f2bf(v * 0.125f);
                    else if (which == 1) kb[(bhh * 2048 + n) * 64 + d] = f2bf(v);
                    else                 vb[(bhh * 64 + d) * 2048 + n] = f2bf(v);
                } else if (EPI == 1) {
                    v = 0.5f * v * (1.f + erff(v * 0.70710678118654752f));
                    outB[(size_t)grow * N + gcol] = f2bf(v);
                } else {
                    v += res[(size_t)grow * N + gcol];
                    outF[(size_t)grow * N + gcol] = v;
                }
            }
        }
    }
}

// ---------- MFMA flash attention: static dbuf, Q-frags hoisted, barrier at tile end ----------
#define PREFETCH(K0N, KSN, VTN)                                                   \
    {                                                                             \
        const ushort_t* kbase_ = kb + (bh * 2048 + (K0N)) * 64;                   \
        const ushort_t* vbase_ = vb + bh * 131072 + (K0N);                        \
        int c0_ = t, r0_ = c0_ >> 3, b0_ = c0_ & 7;                               \
        gload_lds16(kbase_ + (r0_ << 6) + ((b0_ ^ (r0_ & 7)) << 3), &KSN[c0_ * 8]); \
        gload_lds16(vbase_ + (size_t)r0_ * 2048 + ((b0_ ^ (r0_ & 7)) << 3), &VTN[c0_ * 8]); \
        int c1_ = 256 + t, r1_ = c1_ >> 3, b1_ = c1_ & 7;                         \
        gload_lds16(kbase_ + (r1_ << 6) + ((b1_ ^ (r1_ & 7)) << 3), &KSN[c1_ * 8]); \
        gload_lds16(vbase_ + (size_t)r1_ * 2048 + ((b1_ ^ (r1_ & 7)) << 3), &VTN[c1_ * 8]); \
    }

#define ATTN_TILE(KT, KSC, VTC, KSN, VTN)                                         \
    {                                                                             \
        if ((KT) < 31) PREFETCH(((KT) + 1) * 64, KSN, VTN)                        \
        float gjv_[4];                                                            \
        gjv_[0] = G[b * 2048 + (KT) * 64 + cl];                                   \
        gjv_[1] = G[b * 2048 + (KT) * 64 + 16 + cl];                              \
        gjv_[2] = G[b * 2048 + (KT) * 64 + 32 + cl];                              \
        gjv_[3] = G[b * 2048 + (KT) * 64 + 48 + cl];                              \
        floatx4 s_[4];                                                            \
        s_[0] = c2init; s_[1] = c2init; s_[2] = c2init; s_[3] = c2init;           \
        _Pragma("unroll")                                                         \
        for (int kh = 0; kh < 2; kh++) {                                          \
            short8 aq_ = (kh == 0) ? aq0 : aq1;                                   \
            _Pragma("unroll")                                                     \
            for (int nt = 0; nt < 4; nt++) {                                      \
                short8 bk_ = *(const short8*)&KSC[((nt * 16 + cl) << 6) + (((kh * 4 + quad) ^ (cl & 7)) << 3)]; \
                s_[nt] = __builtin_amdgcn_mfma_f32_16x16x32_bf16(aq_, bk_, s_[nt], 0, 0, 0); \
            }                                                                     \
        }                                                                         \
        _Pragma("unroll")                                                         \
        for (int rg = 0; rg < 4; rg++) {                                          \
            int prow_ = wid * 16 + quad * 4 + rg;                                 \
            int r8_ = prow_ & 7, pb_ = prow_ << 6, cs_ = cl & 7, ch_ = cl >> 3;   \
            _Pragma("unroll")                                                     \
            for (int nt = 0; nt < 4; nt++) {                                      \
                float tf_ = __expf(s_[nt][rg]);                                   \
                float p_  = tf_ * __builtin_amdgcn_rcpf(gi[rg] + gjv_[nt]);       \
                sem[rg] += p_;                                                    \
                Ps[pb_ + (((nt * 2 + ch_) ^ r8_) << 3) + cs_] = (ushort_t)(__float_as_uint(p_) >> 16); \
            }                                                                     \
        }                                                                         \
        _Pragma("unroll")                                                         \
        for (int kh = 0; kh < 2; kh++) {                                          \
            short8 ap_ = *(const short8*)&Ps[((wid * 16 + cl) << 6) + (((kh * 4 + quad) ^ (cl & 7)) << 3)]; \
            _Pragma("unroll")                                                     \
            for (int dt = 0; dt < 4; dt++) {                                      \
                short8 bv_ = *(const short8*)&VTC[((dt * 16 + cl) << 6) + (((kh * 4 + quad) ^ (cl & 7)) << 3)]; \
                o[dt] = __builtin_amdgcn_mfma_f32_16x16x32_bf16(ap_, bv_, o[dt], 0, 0, 0); \
            }                                                                     \
        }                                                                         \
        __syncthreads();                                                          \
    }

__launch_bounds__(256)
__global__ void attn_mfma(const ushort_t* __restrict__ qb, const ushort_t* __restrict__ kb,
                          const ushort_t* __restrict__ vb, const float* __restrict__ G,
                          const float* __restrict__ C2, ushort_t* __restrict__ attn) {
    __shared__ __align__(16) ushort_t Qs[4096];
    __shared__ __align__(16) ushort_t Ks0[4096];
    __shared__ __align__(16) ushort_t Ks1[4096];
    __shared__ __align__(16) ushort_t Vt0[4096];
    __shared__ __align__(16) ushort_t Vt1[4096];
    __shared__ __align__(16) ushort_t Ps[4096];
    int qt = blockIdx.x, h = blockIdx.y, b = blockIdx.z;
    int t = threadIdx.x, wid = t >> 6, lane = t & 63;
    int cl = lane & 15, quad = lane >> 4;
    int q0 = qt * 64;
    size_t bh = (size_t)(b * 12 + h);

    const ushort_t* qbase = qb + (bh * 2048 + q0) * 64;
    #pragma unroll
    for (int i = 0; i < 2; i++) {
        int c = i * 256 + t, row = c >> 3, blk = c & 7;
        gload_lds16(qbase + (row << 6) + ((blk ^ (row & 7)) << 3), &Qs[c * 8]);
    }
    int qrow4 = b * 2048 + q0 + wid * 16 + quad * 4;
    float4 g4  = *(const float4*)(G  + qrow4);
    float4 c24 = *(const float4*)(C2 + qrow4);
    float gi[4]  = {g4.x, g4.y, g4.z, g4.w};
    floatx4 c2init = {c24.x, c24.y, c24.z, c24.w};

    PREFETCH(0, Ks0, Vt0)
    __syncthreads();   // Q + tile0 resident

    short8 aq0 = *(const short8*)&Qs[((wid * 16 + cl) << 6) + ((quad ^ (cl & 7)) << 3)];
    short8 aq1 = *(const short8*)&Qs[((wid * 16 + cl) << 6) + (((4 + quad) ^ (cl & 7)) << 3)];

    floatx4 o[4];
    #pragma unroll
    for (int j = 0; j < 4; j++) { floatx4 z = {0.f, 0.f, 0.f, 0.f}; o[j] = z; }
    float sem[4] = {0.f, 0.f, 0.f, 0.f};

    for (int kt = 0; kt < 32; kt += 2) {
        ATTN_TILE(kt,     Ks0, Vt0, Ks1, Vt1)
        ATTN_TILE(kt + 1, Ks1, Vt1, Ks0, Vt0)
    }

    #pragma unroll
    for (int rg = 0; rg < 4; rg++) {
        float m = sem[rg];
        #pragma unroll
        for (int off = 1; off < 16; off <<= 1) m += __shfl_xor(m, off);
        float inv = __builtin_amdgcn_rcpf(m);
        int grow = b * 2048 + q0 + wid * 16 + quad * 4 + rg;
        #pragma unroll
        for (int dt = 0; dt < 4; dt++)
            attn[(size_t)grow * 768 + h * 64 + dt * 16 + cl] = f2bf(o[dt][rg] * inv);
    }
}

extern "C" void kernel_launch(void* const* d_in, const int* in_sizes, int n_in,
                              void* d_out, int out_size, void* d_ws, size_t ws_size,
                              hipStream_t stream) {
    const float* x      = (const float*)d_in[0];
    const float* elev   = (const float*)d_in[1];
    const float* qkv_w  = (const float*)d_in[2];
    const float* qkv_b  = (const float*)d_in[3];
    const float* proj_w = (const float*)d_in[4];
    const float* proj_b = (const float*)d_in[5];
    const float* ln1_g  = (const float*)d_in[6];
    const float* ln1_b  = (const float*)d_in[7];
    const float* ln2_g  = (const float*)d_in[8];
    const float* ln2_b  = (const float*)d_in[9];
    const float* fc1_w  = (const float*)d_in[10];
    const float* fc1_b  = (const float*)d_in[11];
    const float* fc2_w  = (const float*)d_in[12];
    const float* fc2_b  = (const float*)d_in[13];
    const float* barrier= (const float*)d_in[14];
    float* out = (float*)d_out;
    char* ws = (char*)d_ws;

    ushort_t* h    = (ushort_t*)(ws + 0);
    ushort_t* qb   = (ushort_t*)(ws + 6291456);
    ushort_t* kb   = (ushort_t*)(ws + 12582912);
    ushort_t* vb   = (ushort_t*)(ws + 18874368);
    ushort_t* f1   = (ushort_t*)(ws + 0);         // overlays h,qb,kb,vb
    ushort_t* attn = (ushort_t*)(ws + 25165824);
    ushort_t* h2   = (ushort_t*)(ws + 31457280);
    float*    Gf   = (float*)(ws + 31457280);     // overlays h2 region, dead before ln2
    float*    C2f  = (float*)(ws + 31473664);
    ushort_t* qkvT = (ushort_t*)(ws + 37748736);
    ushort_t* projT= (ushort_t*)(ws + 41287680);
    ushort_t* fc1T = (ushort_t*)(ws + 42467328);
    ushort_t* fc2T = (ushort_t*)(ws + 47185920);

    prep_all<<<5840, 256, 0, stream>>>(qkv_w, proj_w, fc1_w, fc2_w, qkvT, projT, fc1T, fc2T,
                                       elev, barrier, Gf, C2f, x, ln1_g, ln1_b, h);
    gemm16<0><<<dim3(18, 32), 256, 0, stream>>>(
        h, qkvT, qkv_b, nullptr, nullptr, nullptr, qb, kb, vb, 2304, 768);
    attn_mfma<<<dim3(32, HEADS, 2), 256, 0, stream>>>(qb, kb, vb, Gf, C2f, attn);
    gemm16<2><<<dim3(6, 32), 256, 0, stream>>>(
        attn, projT, proj_b, nullptr, x, out, nullptr, nullptr, nullptr, 768, 768);
    ln_kernel<<<ROWS, 256, 0, stream>>>(out, ln2_g, ln2_b, h2);
    gemm16<1><<<dim3(24, 32), 256, 0, stream>>>(
        h2, fc1T, fc1_b, f1, nullptr, nullptr, nullptr, nullptr, nullptr, 3072, 768);
    gemm16<2><<<dim3(6, 32), 256, 0, stream>>>(
        f1, fc2T, fc2_b, nullptr, out, out, nullptr, nullptr, nullptr, 768, 3072);
}